// Round 12
// baseline (231.612 us; speedup 1.0000x reference)
//
#include <hip/hip_runtime.h>

#define B_  4
#define S_  2048
#define D_  1024
#define H_  16
#define DH_ 64
#define M_  (B_ * S_)   // 8192 rows

typedef __attribute__((ext_vector_type(8))) short short8;
typedef __attribute__((ext_vector_type(4))) float floatx4;

// ---------- bf16 helpers ----------
__device__ __forceinline__ unsigned short f2bf(float f) {
    union { float f; unsigned int i; } v; v.f = f;
    unsigned int r = v.i + 0x7fffu + ((v.i >> 16) & 1u);   // RNE
    return (unsigned short)(r >> 16);
}
// truncation pack: two fp32 -> packed bf16x2 (P-weight trunc noise ~3e-5,
// harness-verified). Single v_perm_b32.
__device__ __forceinline__ unsigned int pk_trunc(float a, float b) {
#if __has_builtin(__builtin_amdgcn_perm)
    return __builtin_amdgcn_perm(__float_as_uint(b), __float_as_uint(a), 0x07060302u);
#else
    return (__float_as_uint(a) >> 16) | (__float_as_uint(b) & 0xffff0000u);
#endif
}

// raw 2^x (v_exp_f32). Q pre-scaled by 0.125*log2(e) in the GEMM epilogue.
#if __has_builtin(__builtin_amdgcn_exp2f)
#define EXP2(x) __builtin_amdgcn_exp2f(x)
#else
#define EXP2(x) __expf(0.6931471805599453f * (x))
#endif

// ---------- async global->LDS, 16B per lane ----------
typedef const __attribute__((address_space(1))) unsigned int* gas_ptr;
typedef __attribute__((address_space(3))) unsigned int* las_ptr;
__device__ __forceinline__ void async_cp16(const void* g, void* l) {
    __builtin_amdgcn_global_load_lds((gas_ptr)g, (las_ptr)l, 16, 0, 0);
}

#define VMC4 asm volatile("s_waitcnt vmcnt(4)" ::: "memory")
#define VMC0 asm volatile("s_waitcnt vmcnt(0)" ::: "memory")

// ---------- fused prep: x cast (blocks 0..8191) + W cast-transpose (8192..8959) ----------
__global__ __launch_bounds__(256) void cast_fused_kernel(
    const float* __restrict__ x, unsigned short* __restrict__ Ax,
    const float* __restrict__ W0, const float* __restrict__ W1,
    const float* __restrict__ W2,
    unsigned short* __restrict__ T0, unsigned short* __restrict__ T1,
    unsigned short* __restrict__ T2)
{
    const int bid = blockIdx.x;
    const int t = threadIdx.x;
    if (bid < 8192) {
        int i4 = bid * 256 + t;
        float4 v = reinterpret_cast<const float4*>(x)[i4];
        ushort4 o;
        o.x = f2bf(v.x); o.y = f2bf(v.y); o.z = f2bf(v.z); o.w = f2bf(v.w);
        reinterpret_cast<ushort4*>(Ax)[i4] = o;
        return;
    }
    const int idx = bid - 8192;               // 0..767
    const int z   = idx >> 8;                 // 0..2
    const int rem = idx & 255;
    const float* W = z == 0 ? W0 : (z == 1 ? W1 : W2);
    unsigned short* Wt = z == 0 ? T0 : (z == 1 ? T1 : T2);

    __shared__ unsigned short T[64][72];
    const int k0 = (rem & 15) * 64, n0 = (rem >> 4) * 64;

    #pragma unroll
    for (int p = 0; p < 4; ++p) {
        int kr = p * 16 + (t >> 4);
        int nc = (t & 15) * 4;
        float4 v = *reinterpret_cast<const float4*>(W + (size_t)(k0 + kr) * D_ + n0 + nc);
        T[nc + 0][kr] = f2bf(v.x);
        T[nc + 1][kr] = f2bf(v.y);
        T[nc + 2][kr] = f2bf(v.z);
        T[nc + 3][kr] = f2bf(v.w);
    }
    __syncthreads();

    const int nl = t >> 2, kc = (t & 3) * 16;
    size_t base = (size_t)(n0 + nl) * D_ + k0 + kc;
    *reinterpret_cast<short8*>(Wt + base)     = *reinterpret_cast<const short8*>(&T[nl][kc]);
    *reinterpret_cast<short8*>(Wt + base + 8) = *reinterpret_cast<const short8*>(&T[nl][kc + 8]);
}

// ---------- fused QKV GEMM v4: BM=128 x BN=384 geometry + R3's 8-phase interleave ----------
// Per-phase cost ledger (cy/phase / MFMA-per-phase): R3 8ph-256^2 = 1451/16
// (91/MFMA, best); R8 4ph = 1787/16 (112); R11 4ph-BN384 = 2984/24 (124).
// R3's fine interleave (M-half split, bfr persisted across M-phases, one
// stage unit per phase) is the best measured pipeline; its only flaw was the
// 75%-packed 384-block grid. R11's geometry (512 blocks = 2 full rounds,
// A read 8x, FETCH 71.8MB -- verified minimal) fixes packing. v4 = R11
// geometry + R3 phase schedule, verbatim: phase = (K-half, M-half), af[2] x
// bfr[6] = 12 MFMA; bfr loaded at mh==0, reused at mh==1. Stage units
// alternate A(1 cp16)/B(3 cp16) per phase; queue at ph4: [T1h0(4), ph1(1),
// ph2(3), ph3(1), ph4(3)]=12, VMC4 drains exactly all of T1; ph8 likewise
// drains exactly T2 (R3's proven hazard algebra, A/B-split re-derived).
// Geometry, slot-XOR layout, epilogue unchanged from R11.
__global__ __launch_bounds__(512, 2) void gemm_qkv_mfma(
    const unsigned short* __restrict__ Ax,
    const unsigned short* __restrict__ Wt,    // [3072][1024] = Q,K,V weights^T
    const float* __restrict__ bq, const float* __restrict__ bk,
    const float* __restrict__ bv,
    unsigned short* __restrict__ Q,           // Q,K contiguous (K = Q + M_*D_)
    unsigned short* __restrict__ Vtg)
{
    __shared__ unsigned short lds[65536];     // 128 KB

    const int tid  = threadIdx.x;             // 0..511
    const int lane = tid & 63;
    const int w    = tid >> 6;                // 0..7
    const int wm   = w >> 2;                  // 0..1  (64-row half of BM=128)
    const int wn   = w & 3;                   // 0..3  (96-col quarter of BN=384)
    const int l15  = lane & 15, quad = lane >> 4;

    // stage constants: lane-linear LDS dest, slot-XOR applied to global source
    const int pl   = tid >> 3;                // 0..63
    const int sl   = tid & 7;
    const int xx   = sl ^ (pl & 7);
    const int sro  = pl * 2 + (xx >> 2);      // logical row 0..127 in sweep
    const int sc   = (xx & 3) * 8;            // k-chunk (shorts)
    // fragment-read offset (same XOR)
    const int fb = (l15 >> 1) * 64 + ((((l15 & 1) << 2) | quad) ^ (l15 >> 1)) * 8;

    const int id  = blockIdx.x;
    const int g   = (id & 7) * 64 + (id >> 3);    // 512 = 8 XCD x 64, bijective
    const int nb  = g >> 6;                   // 0..7  (== XCD id)
    const int mb  = g & 63;                   // 0..63
    const int m0  = mb * 128;
    const int n0g = nb * 384;                 // global col in [0,3072)

    // region bases (shorts): buf0 A0=0 A1=4096 B0=8192 B1=20480; buf1 +32768
    #define ASTG(kcol, reg) \
        async_cp16(Ax + (size_t)(m0 + sro) * 1024 + (kcol) + sc, lds + (reg) + tid * 8)
    #define BSTG(kcol, reg) do { \
        async_cp16(Wt + (size_t)(n0g + sro) * 1024 + (kcol) + sc,       lds + (reg) + tid * 8); \
        async_cp16(Wt + (size_t)(n0g + 128 + sro) * 1024 + (kcol) + sc, lds + (reg) + 4096 + tid * 8); \
        async_cp16(Wt + (size_t)(n0g + 256 + sro) * 1024 + (kcol) + sc, lds + (reg) + 8192 + tid * 8); \
    } while (0)

    floatx4 acc[4][6] = {};
    short8 bfr[6];

    // prologue: tile0 both halves + tile1 h0 (12 cp16); VMC4 leaves T1.h0's 4 in flight
    ASTG(0, 0);      BSTG(0, 8192);
    ASTG(32, 4096);  BSTG(32, 20480);
    ASTG(64, 32768); BSTG(64, 40960);
    VMC4;
    __builtin_amdgcn_s_barrier();

    #define PH(bufS, ksub, mh, STAGE_STMT, WAIT_STMT) do { \
        short8 af[2]; \
        _Pragma("unroll") \
        for (int i = 0; i < 2; ++i) \
            af[i] = *reinterpret_cast<const short8*>(lds + (bufS) + (ksub) * 4096 + wm * 2048 + ((mh) * 2 + i) * 512 + fb); \
        if ((mh) == 0) { \
            _Pragma("unroll") \
            for (int j = 0; j < 6; ++j) \
                bfr[j] = *reinterpret_cast<const short8*>(lds + (bufS) + 8192 + (ksub) * 12288 + (wn * 6 + j) * 512 + fb); \
        } \
        STAGE_STMT; \
        __builtin_amdgcn_s_barrier(); \
        asm volatile("s_waitcnt lgkmcnt(0)" ::: "memory"); \
        __builtin_amdgcn_sched_barrier(0); \
        __builtin_amdgcn_s_setprio(1); \
        _Pragma("unroll") \
        for (int i = 0; i < 2; ++i) \
            _Pragma("unroll") \
            for (int j = 0; j < 6; ++j) \
                acc[(mh) * 2 + i][j] = __builtin_amdgcn_mfma_f32_16x16x32_bf16(af[i], bfr[j], acc[(mh) * 2 + i][j], 0, 0, 0); \
        __builtin_amdgcn_s_setprio(0); \
        WAIT_STMT; \
        __builtin_amdgcn_s_barrier(); \
    } while (0)

    #pragma unroll 1
    for (int it = 0; it < 8; ++it) {
        const bool nl = (it < 7);
        const int  kA = (2 * it + 1) * 64;    // odd tile k-col
        const int  kB = kA + 64;
        const int  kC = kA + 128;
        // phases 1-4: compute buf0 (tile 2it); 5-8: buf1 (tile 2it+1)
        PH(0,     0, 0, ASTG(kA + 32, 36864), );
        PH(0,     0, 1, BSTG(kA + 32, 53248), );
        PH(0,     1, 0, if (nl) ASTG(kB, 0), );
        PH(0,     1, 1, if (nl) BSTG(kB, 8192), { if (nl) VMC4; else VMC0; });
        PH(32768, 0, 0, if (nl) ASTG(kB + 32, 4096), );
        PH(32768, 0, 1, if (nl) BSTG(kB + 32, 20480), );
        PH(32768, 1, 0, if (nl) ASTG(kC, 32768), );
        PH(32768, 1, 1, if (nl) BSTG(kC, 40960), { if (nl) VMC4; });
    }

    // epilogue: per-fragment matrix select (BN=384 straddles 1024-col bounds)
    const int bI    = m0 >> 11;
    const int sbase = (m0 & 2047) + wm * 64;
    #pragma unroll
    for (int j = 0; j < 6; ++j) {
        const int gc0 = n0g + wn * 96 + j * 16;   // fragment base col (16-aligned)
        const int mt  = gc0 >> 10;                // 0=Q 1=K 2=V, wave-uniform
        const int cm  = (gc0 & 1023) + l15;       // col within its matrix
        const float bb = (mt == 0 ? bq : (mt == 1 ? bk : bv))[cm];
        if (mt == 2) {
            #pragma unroll
            for (int i = 0; i < 4; ++i) {
                int srow = sbase + i * 16 + quad * 4;
                ushort4 o;
                o.x = f2bf(acc[i][j][0] + bb);
                o.y = f2bf(acc[i][j][1] + bb);
                o.z = f2bf(acc[i][j][2] + bb);
                o.w = f2bf(acc[i][j][3] + bb);
                *reinterpret_cast<ushort4*>(Vtg + (size_t)(bI * 1024 + cm) * S_ + srow) = o;
            }
        } else {
            unsigned short* C = Q + (size_t)mt * M_ * D_;
            // Q scale folds softmax 1/sqrt(64) AND exp->exp2 log2(e)
            const float scq = (mt == 0) ? 0.18033688011112042f : 1.0f;
            #pragma unroll
            for (int i = 0; i < 4; ++i)
                #pragma unroll
                for (int r = 0; r < 4; ++r) {
                    int row = m0 + wm * 64 + i * 16 + quad * 4 + r;
                    C[(size_t)row * D_ + cm] = f2bf((acc[i][j][r] + bb) * scq);
                }
        }
    }
}

// ---------- MFMA flash attention v11 (R11): KT=128, conflict-free XOR LDS ----------
// R11 verified: attn below top-5 (<79.4us). Kept as-is.
#define KT_   128
#define NT_   (S_ / KT_)
#define SWZK(row, col) (((row) << 6) + ((col) ^ (((row) & 7) << 3)))
#define SWZV(row, col) (((row) << 7) + ((col) ^ (((row) & 7) << 3)))

__global__ __launch_bounds__(256, 4) void attn_mfma(
    const unsigned short* __restrict__ Qg,
    const unsigned short* __restrict__ Kg,
    const unsigned short* __restrict__ Vtg,   // [(b*16+h)*64+d][s]
    float* __restrict__ out)
{
    __shared__ unsigned short Ks[KT_ * 64];      // [key][d], XOR-swizzled     (16 KB)
    __shared__ unsigned short Vt[DH_ * 128];     // [d][k'], permuted+swizzled (16 KB)

    const int tid  = threadIdx.x;
    const int wq   = tid >> 6;
    const int lane = tid & 63;
    const int l15  = lane & 15;
    const int quad = lane >> 4;

    // XCD swizzle: 1024 = 8 xcd x 8 bh x 16 qt; per-XCD K/V footprint 4MB = L2
    const int id  = blockIdx.x;
    const int bh  = (id & 7) * 8 + ((id >> 3) & 7);
    const int qt  = id >> 6;                  // 0..15
    const int b   = bh >> 4;
    const int colbase = (bh & 15) * DH_;
    const int rowQ0 = b * S_ + qt * 128;

    short8 qf[2][2];
    #pragma unroll
    for (int g = 0; g < 2; ++g) {
        int qrow = rowQ0 + wq * 32 + g * 16 + l15;
        qf[g][0] = *reinterpret_cast<const short8*>(Qg + (size_t)qrow * D_ + colbase + quad * 8);
        qf[g][1] = *reinterpret_cast<const short8*>(Qg + (size_t)qrow * D_ + colbase + 32 + quad * 8);
    }

    // all-ones bf16 B-fragment for the denominator MFMA
    short8 vones;
    #pragma unroll
    for (int i = 0; i < 8; ++i) vones[i] = (short)0x3F80;

    floatx4 Oacc[2][4] = {};
    floatx4 Lacc[2] = {};

    // staging: thread covers rows p*32+srow, 16B key-chunk sc8
    const int srow = tid >> 3;        // 0..31
    const int sc8  = (tid & 7) * 8;
    const int vc  = sc8 >> 4;
    const int vqk = (sc8 >> 2) & 3;   // 0 or 2
    const int vk0 = ((vc & 1) << 2) + ((vc >> 1) << 5) + (vqk << 3);

    const unsigned short* Kbase = Kg + (size_t)(b * S_) * D_ + colbase;
    const unsigned short* Vbase = Vtg + (size_t)(bh * 64) * S_;

    short8 kpre[4], vpre[2][2];
    #pragma unroll
    for (int p = 0; p < 4; ++p)
        kpre[p] = *reinterpret_cast<const short8*>(Kbase + (size_t)(p * 32 + srow) * D_ + sc8);
    #pragma unroll
    for (int p = 0; p < 2; ++p)
        #pragma unroll
        for (int q = 0; q < 2; ++q)
            vpre[p][q] = *reinterpret_cast<const short8*>(Vbase + (size_t)(p * 32 + srow) * S_ + q * 64 + sc8);

    for (int kt = 0; kt < NT_; ++kt) {
        __syncthreads();
        #pragma unroll
        for (int p = 0; p < 4; ++p)
            *reinterpret_cast<short8*>(&Ks[SWZK(p * 32 + srow, sc8)]) = kpre[p];
        #pragma unroll
        for (int p = 0; p < 2; ++p)
            #pragma unroll
            for (int q = 0; q < 2; ++q) {
                int r = p * 32 + srow;
                uint4 u = __builtin_bit_cast(uint4, vpre[p][q]);
                uint2 lo, hi;
                lo.x = u.x; lo.y = u.y; hi.x = u.z; hi.y = u.w;
                *reinterpret_cast<uint2*>(&Vt[SWZV(r, q * 64 + vk0)])     = lo;
                *reinterpret_cast<uint2*>(&Vt[SWZV(r, q * 64 + vk0 + 8)]) = hi;
            }
        __syncthreads();
        // issue-early: next tile's global loads AFTER the publish barrier;
        // they complete under this tile's ~2x compute.
        if (kt + 1 < NT_) {
            int off = (kt + 1) * KT_;
            #pragma unroll
            for (int p = 0; p < 4; ++p)
                kpre[p] = *reinterpret_cast<const short8*>(Kbase + (size_t)(off + p * 32 + srow) * D_ + sc8);
            #pragma unroll
            for (int p = 0; p < 2; ++p)
                #pragma unroll
                for (int q = 0; q < 2; ++q)
                    vpre[p][q] = *reinterpret_cast<const short8*>(Vbase + (size_t)(p * 32 + srow) * S_ + off + q * 64 + sc8);
        }

        // process 32 keys (= one PV MFMA's K) per half; 4 halves per tile
        #pragma unroll
        for (int half = 0; half < 4; ++half) {
            floatx4 s_[2][2];
            __builtin_amdgcn_s_setprio(1);
            #pragma unroll
            for (int ci = 0; ci < 2; ++ci) {
                int kr = (half * 2 + ci) * 16 + l15;
                short8 kf0 = *reinterpret_cast<const short8*>(&Ks[SWZK(kr, quad * 8)]);
                short8 kf1 = *reinterpret_cast<const short8*>(&Ks[SWZK(kr, 32 + quad * 8)]);
                #pragma unroll
                for (int g = 0; g < 2; ++g) {
                    floatx4 a = {0.f, 0.f, 0.f, 0.f};
                    a = __builtin_amdgcn_mfma_f32_16x16x32_bf16(kf0, qf[g][0], a, 0, 0, 0);
                    a = __builtin_amdgcn_mfma_f32_16x16x32_bf16(kf1, qf[g][1], a, 0, 0, 0);
                    s_[g][ci] = a;
                }
            }
            __builtin_amdgcn_s_setprio(0);
            // exp2 + pack directly into the K=32 A-fragment (k' order)
            short8 pa[2];
            #pragma unroll
            for (int g = 0; g < 2; ++g) {
                float p00 = EXP2(s_[g][0][0]), p01 = EXP2(s_[g][0][1]);
                float p02 = EXP2(s_[g][0][2]), p03 = EXP2(s_[g][0][3]);
                float p10 = EXP2(s_[g][1][0]), p11 = EXP2(s_[g][1][1]);
                float p12 = EXP2(s_[g][1][2]), p13 = EXP2(s_[g][1][3]);
                uint4 pu;
                pu.x = pk_trunc(p00, p01);
                pu.y = pk_trunc(p02, p03);
                pu.z = pk_trunc(p10, p11);
                pu.w = pk_trunc(p12, p13);
                pa[g] = __builtin_bit_cast(short8, pu);
            }
            // denominator + PV on the matrix pipe
            __builtin_amdgcn_s_setprio(1);
            #pragma unroll
            for (int g = 0; g < 2; ++g)
                Lacc[g] = __builtin_amdgcn_mfma_f32_16x16x32_bf16(pa[g], vones, Lacc[g], 0, 0, 0);
            #pragma unroll
            for (int d = 0; d < 4; ++d) {
                short8 vf = *reinterpret_cast<const short8*>(
                    &Vt[SWZV(d * 16 + l15, half * 32 + quad * 8)]);
                #pragma unroll
                for (int g = 0; g < 2; ++g)
                    Oacc[g][d] = __builtin_amdgcn_mfma_f32_16x16x32_bf16(pa[g], vf, Oacc[g][d], 0, 0, 0);
            }
            __builtin_amdgcn_s_setprio(0);
        }
    }

    // epilogue: Lacc[g][r] is already the full row sum (no cross-lane reduce)
    #pragma unroll
    for (int g = 0; g < 2; ++g) {
        int orow = rowQ0 + wq * 32 + g * 16 + quad * 4;
        #pragma unroll
        for (int r = 0; r < 4; ++r) {
            float inv = 1.f / Lacc[g][r];
            #pragma unroll
            for (int d = 0; d < 4; ++d)
                out[(size_t)(orow + r) * D_ + colbase + d * 16 + l15] = Oacc[g][d][r] * inv;
        }
    }
}

extern "C" void kernel_launch(void* const* d_in, const int* in_sizes, int n_in,
                              void* d_out, int out_size, void* d_ws, size_t ws_size,
                              hipStream_t stream) {
    const float* x  = (const float*)d_in[0];
    const float* Wq = (const float*)d_in[1];
    const float* bq = (const float*)d_in[2];
    const float* Wk = (const float*)d_in[3];
    const float* bk = (const float*)d_in[4];
    const float* Wv = (const float*)d_in[5];
    const float* bv = (const float*)d_in[6];
    float* out = (float*)d_out;

    unsigned short* Q   = (unsigned short*)d_ws;
    unsigned short* K   = Q + (size_t)M_ * D_;
    unsigned short* Vtg = K + (size_t)M_ * D_;
    unsigned short* Ax  = Vtg + (size_t)M_ * D_;
    unsigned short* Wtq = Ax + (size_t)M_ * D_;   // Wtq,Wtk,Wtv contiguous [3072][1024]
    unsigned short* Wtk = Wtq + (size_t)D_ * D_;
    unsigned short* Wtv = Wtk + (size_t)D_ * D_;

    cast_fused_kernel<<<8192 + 768, 256, 0, stream>>>(x, Ax, Wq, Wk, Wv, Wtq, Wtk, Wtv);

    gemm_qkv_mfma<<<512, 512, 0, stream>>>(Ax, Wtq, bq, bk, bv, Q, Vtg);

    attn_mfma<<<1024, 256, 0, stream>>>(Q, K, Vtg, out);
}